// Round 2
// baseline (1073.675 us; speedup 1.0000x reference)
//
#include <hip/hip_runtime.h>
#include <hip/hip_bf16.h>
#include <cstdint>
#include <cstddef>

#define HDIM 128
#define NLEAVES 65536
#define NLEVELS 16
#define TOTAL_NODES 131071   // 2*NLEAVES - 1

using s8v  = __attribute__((ext_vector_type(8))) short;
using f4v  = __attribute__((ext_vector_type(4))) float;

__device__ __forceinline__ short f2bf(float f){
  __hip_bfloat16 b = __float2bfloat16(f);
  return *reinterpret_cast<short*>(&b);
}
__device__ __forceinline__ float bf2f(short s){
  unsigned int u = ((unsigned int)(unsigned short)s) << 16;
  return __uint_as_float(u);
}
__device__ __forceinline__ float sigm(float x){ return 1.0f/(1.0f + __expf(-x)); }
__device__ __forceinline__ float tanh_(float x){
  float a = fabsf(x);
  float t = __expf(-2.0f*a);
  float r = (1.0f - t)/(1.0f + t);
  return copysignf(r, x);
}

// ---------------------------------------------------------------------------
// Build bf16 weight blocks in workspace.
// Wl: [384][128]  rows 0-127 = W_i, 128-255 = W_o, 256-383 = W_u
// Wc: [640][256]  rows: U_i, U_o, U_u, [F1 | 0], [0 | F2]
// bl: [384], bc: [640]
// ---------------------------------------------------------------------------
__global__ __launch_bounds__(256) void prep_weights(
    const float* __restrict__ Wi, const float* __restrict__ bi,
    const float* __restrict__ Wo, const float* __restrict__ bo,
    const float* __restrict__ Wu, const float* __restrict__ bu,
    const float* __restrict__ Ui, const float* __restrict__ bUi,
    const float* __restrict__ Uo, const float* __restrict__ bUo,
    const float* __restrict__ Uu, const float* __restrict__ bUu,
    const float* __restrict__ F1, const float* __restrict__ bF1,
    const float* __restrict__ F2, const float* __restrict__ bF2,
    short* __restrict__ Wl, short* __restrict__ Wc,
    float* __restrict__ bl, float* __restrict__ bc)
{
  const int gid = blockIdx.x*256 + threadIdx.x;   // grid covers 163840
  if (gid < 640*256){
    const int row = gid >> 8, k = gid & 255;
    const int g = row >> 7, j = row & 127;
    float v;
    if      (g == 0) v = Ui[j*256 + k];
    else if (g == 1) v = Uo[j*256 + k];
    else if (g == 2) v = Uu[j*256 + k];
    else if (g == 3) v = (k < 128) ? F1[j*128 + k] : 0.0f;
    else             v = (k >= 128) ? F2[j*128 + (k-128)] : 0.0f;
    Wc[gid] = f2bf(v);
  }
  if (gid < 384*128){
    const int row = gid >> 7, k = gid & 127;
    const int g = row >> 7, j = row & 127;
    const float v = (g == 0) ? Wi[j*128 + k] : (g == 1) ? Wo[j*128 + k] : Wu[j*128 + k];
    Wl[gid] = f2bf(v);
  }
  if (gid < 640){
    const int g = gid >> 7, j = gid & 127;
    bc[gid] = (g==0)?bUi[j]:(g==1)?bUo[j]:(g==2)?bUu[j]:(g==3)?bF1[j]:bF2[j];
  }
  if (gid < 384){
    const int g = gid >> 7, j = gid & 127;
    bl[gid] = (g==0)?bi[j]:(g==1)?bo[j]:bu[j];
  }
}

// ---------------------------------------------------------------------------
// Gather embed rows -> bf16 x buffer. One thread per 8 elements.
// Grid exactly NLEAVES*16 threads.
// ---------------------------------------------------------------------------
__global__ __launch_bounds__(256) void gather_embed(
    const int* __restrict__ tok, const float* __restrict__ embed,
    short* __restrict__ x)
{
  const int gid  = blockIdx.x*256 + threadIdx.x;
  const int node = gid >> 4;
  const int part = gid & 15;
  const int t = tok[node];
  const float4* s4 = reinterpret_cast<const float4*>(embed + (size_t)t*HDIM + part*8);
  const float4 v0 = s4[0], v1 = s4[1];
  s8v o;
  o[0] = f2bf(v0.x); o[1] = f2bf(v0.y); o[2] = f2bf(v0.z); o[3] = f2bf(v0.w);
  o[4] = f2bf(v1.x); o[5] = f2bf(v1.y); o[6] = f2bf(v1.z); o[7] = f2bf(v1.w);
  *reinterpret_cast<s8v*>(x + (size_t)gid*8) = o;
}

// ---------------------------------------------------------------------------
// One tree level as a GEMM: gates = A[M][K] @ W[G*128][K]^T, then LSTM cell.
// Block: 256 threads = 4 waves; wave handles 32 nodes; block 128 nodes.
// MFMA 16x16x32 bf16. A-frag: row=lane&15, k=(lane>>4)*8+i.
// B-frag: col(=weight row)=lane&15, same k. D: col=lane&15, row=(lane>>4)*4+r.
// ---------------------------------------------------------------------------
template<int K, int G, bool LEAF>
__global__ __launch_bounds__(256) void level_kernel(
    const short* __restrict__ A,      // [M][K] bf16 bits
    const float* __restrict__ c_in,   // [2M][128] (interior only)
    const short* __restrict__ W,      // [G*128][K] bf16 bits
    const float* __restrict__ bias,   // [G*128]
    short* __restrict__ h_out,        // [M][128] bf16 bits
    float* __restrict__ c_out,        // [M][128]
    int M)
{
  constexpr int KT = K/32;
  const int lane = threadIdx.x & 63;
  const int wv   = threadIdx.x >> 6;
  const int m0   = blockIdx.x*128 + wv*32;
  if (m0 >= M) return;                 // no __syncthreads below; safe divergence
  const int r16 = lane & 15;
  const int kg  = lane >> 4;

  // Load A fragments (held across all output tiles)
  s8v a[2][KT];
  #pragma unroll
  for (int ms = 0; ms < 2; ++ms){
    const int m = m0 + ms*16 + r16;
    const bool ok = (m < M);
    const short* ap = A + (size_t)m*K + kg*8;
    #pragma unroll
    for (int kt = 0; kt < KT; ++kt){
      s8v v;
      if (ok) v = *reinterpret_cast<const s8v*>(ap + kt*32);
      else {
        #pragma unroll
        for (int e = 0; e < 8; ++e) v[e] = 0;
      }
      a[ms][kt] = v;
    }
  }

  for (int ct = 0; ct < 8; ++ct){      // 8 channel tiles of 16
    f4v acc[G][2];
    #pragma unroll
    for (int g = 0; g < G; ++g)
      #pragma unroll
      for (int ms = 0; ms < 2; ++ms)
        #pragma unroll
        for (int e = 0; e < 4; ++e) acc[g][ms][e] = 0.0f;

    #pragma unroll
    for (int g = 0; g < G; ++g){
      const short* bp = W + (size_t)(g*128 + ct*16 + r16)*K + kg*8;
      #pragma unroll
      for (int kt = 0; kt < KT; ++kt){
        const s8v b = *reinterpret_cast<const s8v*>(bp + kt*32);
        acc[g][0] = __builtin_amdgcn_mfma_f32_16x16x32_bf16(a[0][kt], b, acc[g][0], 0, 0, 0);
        acc[g][1] = __builtin_amdgcn_mfma_f32_16x16x32_bf16(a[1][kt], b, acc[g][1], 0, 0, 0);
      }
    }

    // LSTM cell elementwise for this channel tile
    const int j = ct*16 + r16;
    const float bi_ = bias[j];
    const float bo_ = bias[HDIM + j];
    const float bu_ = bias[2*HDIM + j];
    float bf1_ = 0.0f, bf2_ = 0.0f;
    if constexpr (!LEAF){ bf1_ = bias[3*HDIM + j]; bf2_ = bias[4*HDIM + j]; }

    #pragma unroll
    for (int ms = 0; ms < 2; ++ms){
      #pragma unroll
      for (int r = 0; r < 4; ++r){
        const int m = m0 + ms*16 + kg*4 + r;
        if (m < M){
          const float iv = sigm(acc[0][ms][r] + bi_);
          const float ov = sigm(acc[1][ms][r] + bo_);
          const float uv = tanh_(acc[2][ms][r] + bu_);
          float c;
          if constexpr (LEAF){
            c = iv*uv;
          } else {
            const float f1 = sigm(acc[3][ms][r] + bf1_);
            const float f2 = sigm(acc[4][ms][r] + bf2_);
            const float cl = c_in[(size_t)(2*m)  *HDIM + j];
            const float cr = c_in[(size_t)(2*m+1)*HDIM + j];
            c = iv*uv + f1*cl + f2*cr;
          }
          const float hv = ov * tanh_(c);
          c_out[(size_t)m*HDIM + j] = c;
          h_out[(size_t)m*HDIM + j] = f2bf(hv);
        }
      }
    }
  }
}

// ---------------------------------------------------------------------------
// Output projection for all nodes + label copy.
// ---------------------------------------------------------------------------
__global__ __launch_bounds__(256) void outproj_kernel(
    const short* __restrict__ h_all,
    const int* __restrict__ labels,
    const float* __restrict__ ow, const float* __restrict__ ob,
    float* __restrict__ out)
{
  __shared__ float wsm[5*HDIM];
  __shared__ float bsm[5];
  for (int i = threadIdx.x; i < 5*HDIM; i += 256) wsm[i] = ow[i];
  if (threadIdx.x < 5) bsm[threadIdx.x] = ob[threadIdx.x];
  __syncthreads();
  const int n = blockIdx.x*256 + threadIdx.x;
  if (n >= TOTAL_NODES) return;
  const s8v* hp = reinterpret_cast<const s8v*>(h_all + (size_t)n*HDIM);
  float acc[5] = {0.f,0.f,0.f,0.f,0.f};
  #pragma unroll
  for (int t = 0; t < 16; ++t){
    const s8v v = hp[t];
    #pragma unroll
    for (int e = 0; e < 8; ++e){
      const float hv = bf2f(v[e]);
      const int j = t*8 + e;
      #pragma unroll
      for (int c5 = 0; c5 < 5; ++c5) acc[c5] += hv * wsm[c5*HDIM + j];
    }
  }
  #pragma unroll
  for (int c5 = 0; c5 < 5; ++c5) out[(size_t)n*5 + c5] = acc[c5] + bsm[c5];
  out[(size_t)TOTAL_NODES*5 + n] = (float)labels[n];
}

// ---------------------------------------------------------------------------
extern "C" void kernel_launch(void* const* d_in, const int* in_sizes, int n_in,
                              void* d_out, int out_size, void* d_ws, size_t ws_size,
                              hipStream_t stream)
{
  (void)in_sizes; (void)n_in; (void)out_size; (void)ws_size;
  const int*   tok    = (const int*)  d_in[0];
  const int*   labels = (const int*)  d_in[1];
  const float* embed  = (const float*)d_in[2];
  const float* Wi  = (const float*)d_in[3];  const float* bi  = (const float*)d_in[4];
  const float* Wo  = (const float*)d_in[5];  const float* bo  = (const float*)d_in[6];
  const float* Wu  = (const float*)d_in[7];  const float* bu  = (const float*)d_in[8];
  const float* Ui  = (const float*)d_in[9];  const float* bUi = (const float*)d_in[10];
  const float* Uo  = (const float*)d_in[11]; const float* bUo = (const float*)d_in[12];
  const float* Uu  = (const float*)d_in[13]; const float* bUu = (const float*)d_in[14];
  const float* F1  = (const float*)d_in[15]; const float* bF1 = (const float*)d_in[16];
  const float* F2  = (const float*)d_in[17]; const float* bF2 = (const float*)d_in[18];
  const float* ow  = (const float*)d_in[19]; const float* ob  = (const float*)d_in[20];
  float* out = (float*)d_out;

  char* ws = (char*)d_ws;
  size_t off = 0;
  auto alloc = [&](size_t bytes) -> void* {
    void* p = ws + off;
    off += (bytes + 255) & ~(size_t)255;
    return p;
  };
  short* h_all = (short*)alloc((size_t)131072*HDIM*2);   // all-level h, bf16
  float* c_a   = (float*)alloc((size_t)65536*HDIM*4);    // c ping
  float* c_b   = (float*)alloc((size_t)32768*HDIM*4);    // c pong
  short* x_bf  = (short*)c_b;                            // x aliases c_b (x dead before c_b written)
  short* Wl    = (short*)alloc((size_t)384*128*2);
  short* Wc    = (short*)alloc((size_t)640*256*2);
  float* bl    = (float*)alloc((size_t)384*4);
  float* bc    = (float*)alloc((size_t)640*4);

  prep_weights<<<640, 256, 0, stream>>>(Wi,bi,Wo,bo,Wu,bu,Ui,bUi,Uo,bUo,Uu,bUu,F1,bF1,F2,bF2,
                                        Wl, Wc, bl, bc);
  gather_embed<<<(NLEAVES*16)/256, 256, 0, stream>>>(tok, embed, x_bf);

  // Leaf level: K=128, gates i,o,u
  level_kernel<128,3,true><<<NLEAVES/128, 256, 0, stream>>>(
      x_bf, nullptr, Wl, bl, h_all, c_a, NLEAVES);

  // Interior levels
  size_t prev_off = 0;
  size_t cur_off  = NLEAVES;
  int N = NLEAVES;
  for (int L = 1; L <= NLEVELS; ++L){
    N >>= 1;
    const short* Aptr = h_all + prev_off*HDIM;
    short*       hout = h_all + cur_off*HDIM;
    float* cin  = (L & 1) ? c_a : c_b;
    float* cout = (L & 1) ? c_b : c_a;
    const int blocks = (N + 127)/128;
    level_kernel<256,5,false><<<blocks, 256, 0, stream>>>(
        Aptr, cin, Wc, bc, hout, cout, N);
    prev_off = cur_off;
    cur_off += N;
  }

  outproj_kernel<<<(TOTAL_NODES + 255)/256, 256, 0, stream>>>(h_all, labels, ow, ob, out);
}

// Round 3
// 664.767 us; speedup vs baseline: 1.6151x; 1.6151x over previous
//
#include <hip/hip_runtime.h>
#include <hip/hip_bf16.h>
#include <cstdint>
#include <cstddef>

#define HDIM 128
#define NLEAVES 65536
#define TOTAL_NODES 131071   // 2*NLEAVES - 1

using s8v  = __attribute__((ext_vector_type(8))) short;
using f4v  = __attribute__((ext_vector_type(4))) float;

__device__ __forceinline__ short f2bf(float f){
  __hip_bfloat16 b = __float2bfloat16(f);
  return *reinterpret_cast<short*>(&b);
}
__device__ __forceinline__ float bf2f(short s){
  unsigned int u = ((unsigned int)(unsigned short)s) << 16;
  return __uint_as_float(u);
}
__device__ __forceinline__ float sigm(float x){ return 1.0f/(1.0f + __expf(-x)); }
__device__ __forceinline__ float tanh_(float x){
  float a = fabsf(x);
  float t = __expf(-2.0f*a);
  float r = (1.0f - t)/(1.0f + t);
  return copysignf(r, x);
}
__device__ __forceinline__ void gload_lds16(const void* g, void* l){
  __builtin_amdgcn_global_load_lds(
      (const __attribute__((address_space(1))) unsigned int*)g,
      (__attribute__((address_space(3))) unsigned int*)l, 16, 0, 0);
}

// ---------------------------------------------------------------------------
// Weight prep.
// Wc_lin  [640][256]      : U_i,U_o,U_u,[F1|0],[0|F2]  (plain, for tail kernel)
// Wc_st   [8][80][256]    : per-ct slice, rows g*16+r16, shorts k ^ ((r16&7)<<3)
// Wl_st   [8][48][128]    : leaf slices, same swizzle
// bl[384], bc[640]
// ---------------------------------------------------------------------------
__global__ __launch_bounds__(256) void prep_weights(
    const float* __restrict__ Wi, const float* __restrict__ bi,
    const float* __restrict__ Wo, const float* __restrict__ bo,
    const float* __restrict__ Wu, const float* __restrict__ bu,
    const float* __restrict__ Ui, const float* __restrict__ bUi,
    const float* __restrict__ Uo, const float* __restrict__ bUo,
    const float* __restrict__ Uu, const float* __restrict__ bUu,
    const float* __restrict__ F1, const float* __restrict__ bF1,
    const float* __restrict__ F2, const float* __restrict__ bF2,
    short* __restrict__ Wc_lin, short* __restrict__ Wc_st,
    short* __restrict__ Wl_st,
    float* __restrict__ bl, float* __restrict__ bc)
{
  const int gid = blockIdx.x*256 + threadIdx.x;   // 640*256 = 163840 threads
  if (gid < 640*256){
    const int row = gid >> 8, k = gid & 255;
    const int g = row >> 7, jj = row & 127;
    const int ct = jj >> 4, r16 = jj & 15;
    float v;
    if      (g == 0) v = Ui[jj*256 + k];
    else if (g == 1) v = Uo[jj*256 + k];
    else if (g == 2) v = Uu[jj*256 + k];
    else if (g == 3) v = (k < 128) ? F1[jj*128 + k] : 0.0f;
    else             v = (k >= 128) ? F2[jj*128 + (k-128)] : 0.0f;
    const short s = f2bf(v);
    Wc_lin[gid] = s;
    Wc_st[ct*20480 + (g*16 + r16)*256 + (k ^ ((r16 & 7) << 3))] = s;
  }
  if (gid < 384*128){
    const int row = gid >> 7, k = gid & 127;
    const int g = row >> 7, jj = row & 127;
    const int ct = jj >> 4, r16 = jj & 15;
    const float v = (g == 0) ? Wi[jj*128 + k] : (g == 1) ? Wo[jj*128 + k] : Wu[jj*128 + k];
    Wl_st[ct*6144 + (g*16 + r16)*128 + (k ^ ((r16 & 7) << 3))] = f2bf(v);
  }
  if (gid < 640){
    const int g = gid >> 7, j = gid & 127;
    bc[gid] = (g==0)?bUi[j]:(g==1)?bUo[j]:(g==2)?bUu[j]:(g==3)?bF1[j]:bF2[j];
  }
  if (gid < 384){
    const int g = gid >> 7, j = gid & 127;
    bl[gid] = (g==0)?bi[j]:(g==1)?bo[j]:bu[j];
  }
}

// ---------------------------------------------------------------------------
// Big level kernel: 256 thr (4 waves), 128 nodes/block (wave = 32 rows).
// B double-buffered in LDS per ct-slice (staged via global_load_lds from
// pre-swizzled layout). M must be a multiple of 128.
// ---------------------------------------------------------------------------
template<int K, int G, bool LEAF>
__global__ __launch_bounds__(256) void level_kernel(
    const short* __restrict__ A,      // interior: prev h [2M? rows][K/2 ch pairs]
    const int*   __restrict__ tok,    // leaf only
    const float* __restrict__ embed,  // leaf only
    const float* __restrict__ c_in,   // interior only
    const short* __restrict__ Wst,    // staged swizzled [8][G*16][K]
    const float* __restrict__ bias,   // [G*128]
    short* __restrict__ h_out,
    float* __restrict__ c_out)
{
  constexpr int KT    = K/32;
  constexpr int SLICE = G*16*K;          // shorts per ct-slice
  constexpr int ITERS = (G*K)/128;       // 16B chunks per thread per stage
  __shared__ short Bst[2][SLICE];

  const int tid  = threadIdx.x;
  const int lane = tid & 63;
  const int wv   = tid >> 6;
  const int r16  = lane & 15;
  const int kg   = lane >> 4;
  const int m0   = blockIdx.x*128 + wv*32;
  const int swz  = (r16 & 7) << 3;

  auto stage = [&](int buf, int ct){
    const short* src = Wst + ct*SLICE;
    #pragma unroll
    for (int i = 0; i < ITERS; ++i){
      const short* g = src + (size_t)(i*256 + tid)*8;
      short* l = &Bst[buf][0] + (i*256 + wv*64)*8;   // wave-uniform base
      gload_lds16(g, l);
    }
  };

  // A fragments, held for whole kernel
  s8v a[2][KT];
  if constexpr (LEAF){
    #pragma unroll
    for (int ms = 0; ms < 2; ++ms){
      const int m = m0 + ms*16 + r16;
      const int t = tok[m];
      const float* ep = embed + (size_t)t*HDIM + kg*8;
      #pragma unroll
      for (int kt = 0; kt < KT; ++kt){
        const float4 v0 = *reinterpret_cast<const float4*>(ep + kt*32);
        const float4 v1 = *reinterpret_cast<const float4*>(ep + kt*32 + 4);
        s8v v;
        v[0]=f2bf(v0.x); v[1]=f2bf(v0.y); v[2]=f2bf(v0.z); v[3]=f2bf(v0.w);
        v[4]=f2bf(v1.x); v[5]=f2bf(v1.y); v[6]=f2bf(v1.z); v[7]=f2bf(v1.w);
        a[ms][kt] = v;
      }
    }
  } else {
    #pragma unroll
    for (int ms = 0; ms < 2; ++ms){
      const short* ap = A + (size_t)(m0 + ms*16 + r16)*K + kg*8;
      #pragma unroll
      for (int kt = 0; kt < KT; ++kt)
        a[ms][kt] = *reinterpret_cast<const s8v*>(ap + kt*32);
    }
  }

  stage(0, 0);
  __syncthreads();

  for (int ct = 0; ct < 8; ++ct){
    const int buf = ct & 1;
    if (ct < 7) stage(buf ^ 1, ct + 1);

    f4v acc[G][2];
    #pragma unroll
    for (int g = 0; g < G; ++g)
      #pragma unroll
      for (int ms = 0; ms < 2; ++ms)
        #pragma unroll
        for (int e = 0; e < 4; ++e) acc[g][ms][e] = 0.0f;

    #pragma unroll
    for (int g = 0; g < G; ++g){
      const short* bp = &Bst[buf][(g*16 + r16)*K];
      #pragma unroll
      for (int kt = 0; kt < KT; ++kt){
        const s8v b = *reinterpret_cast<const s8v*>(bp + ((kg*8 + kt*32) ^ swz));
        acc[g][0] = __builtin_amdgcn_mfma_f32_16x16x32_bf16(a[0][kt], b, acc[g][0], 0, 0, 0);
        acc[g][1] = __builtin_amdgcn_mfma_f32_16x16x32_bf16(a[1][kt], b, acc[g][1], 0, 0, 0);
      }
    }

    // epilogue for channel tile j = ct*16 + r16
    const int j = ct*16 + r16;
    const float bi_ = bias[j];
    const float bo_ = bias[HDIM + j];
    const float bu_ = bias[2*HDIM + j];
    float bf1_ = 0.0f, bf2_ = 0.0f;
    if constexpr (!LEAF){ bf1_ = bias[3*HDIM + j]; bf2_ = bias[4*HDIM + j]; }

    #pragma unroll
    for (int ms = 0; ms < 2; ++ms){
      #pragma unroll
      for (int r = 0; r < 4; ++r){
        const int m = m0 + ms*16 + kg*4 + r;
        const float iv = sigm(acc[0][ms][r] + bi_);
        const float ov = sigm(acc[1][ms][r] + bo_);
        const float uv = tanh_(acc[2][ms][r] + bu_);
        float c;
        if constexpr (LEAF){
          c = iv*uv;
        } else {
          const float f1 = sigm(acc[3][ms][r] + bf1_);
          const float f2 = sigm(acc[4][ms][r] + bf2_);
          const float cl = c_in[(size_t)(2*m)  *HDIM + j];
          const float cr = c_in[(size_t)(2*m+1)*HDIM + j];
          c = iv*uv + f1*cl + f2*cr;
        }
        const float hv = ov * tanh_(c);
        c_out[(size_t)m*HDIM + j] = c;
        h_out[(size_t)m*HDIM + j] = f2bf(hv);
      }
    }
    __syncthreads();
  }
}

// ---------------------------------------------------------------------------
// Fused tail: levels N=64..1 in ONE block (512 thr, 8 waves; wave = ct slice).
// h ping-pongs inside hR (in-place pairwise compaction, barrier-protected);
// c ping-pongs cb0/cb1. Weights read from L2 (Wc_lin).
// ---------------------------------------------------------------------------
template<int N, bool CING>
__device__ __forceinline__ void tail_level(
    int tid,
    const float* __restrict__ cin_g, const float* __restrict__ cin_l,
    float* __restrict__ cout_l,
    short* __restrict__ hR,
    short* __restrict__ hg,            // h_all + off*128
    const short* __restrict__ Wc, const float* __restrict__ bias)
{
  constexpr int NT = (N + 15)/16;
  const int lane = tid & 63;
  const int w    = tid >> 6;          // ct
  const int r16  = lane & 15;
  const int kg   = lane >> 4;

  f4v acc[5][NT];
  #pragma unroll
  for (int g = 0; g < 5; ++g)
    #pragma unroll
    for (int mt = 0; mt < NT; ++mt)
      #pragma unroll
      for (int e = 0; e < 4; ++e) acc[g][mt][e] = 0.0f;

  #pragma unroll
  for (int g = 0; g < 5; ++g){
    s8v b[8];
    const short* bp = Wc + (size_t)(g*128 + w*16 + r16)*256 + kg*8;
    #pragma unroll
    for (int kt = 0; kt < 8; ++kt)
      b[kt] = *reinterpret_cast<const s8v*>(bp + kt*32);
    #pragma unroll
    for (int mt = 0; mt < NT; ++mt){
      const int ar = mt*16 + r16;
      const short* hp = hR + ar*256;
      const int sw = (ar & 7) << 3;
      #pragma unroll
      for (int kt = 0; kt < 8; ++kt){
        const s8v av = *reinterpret_cast<const s8v*>(hp + ((kg*8 + kt*32) ^ sw));
        acc[g][mt] = __builtin_amdgcn_mfma_f32_16x16x32_bf16(av, b[kt], acc[g][mt], 0, 0, 0);
      }
    }
  }

  __syncthreads();   // all hR reads complete before overwrite

  const int j = w*16 + r16;
  const float bi_ = bias[j];
  const float bo_ = bias[HDIM + j];
  const float bu_ = bias[2*HDIM + j];
  const float bf1_ = bias[3*HDIM + j];
  const float bf2_ = bias[4*HDIM + j];

  #pragma unroll
  for (int mt = 0; mt < NT; ++mt){
    #pragma unroll
    for (int r = 0; r < 4; ++r){
      const int m = mt*16 + kg*4 + r;
      if (m < N){
        const float iv = sigm(acc[0][mt][r] + bi_);
        const float ov = sigm(acc[1][mt][r] + bo_);
        const float uv = tanh_(acc[2][mt][r] + bu_);
        const float f1 = sigm(acc[3][mt][r] + bf1_);
        const float f2 = sigm(acc[4][mt][r] + bf2_);
        float cl, cr;
        if constexpr (CING){
          cl = cin_g[(size_t)(2*m)  *HDIM + j];
          cr = cin_g[(size_t)(2*m+1)*HDIM + j];
        } else {
          cl = cin_l[(2*m)  *HDIM + j];
          cr = cin_l[(2*m+1)*HDIM + j];
        }
        const float c = iv*uv + f1*cl + f2*cr;
        const float hv = ov * tanh_(c);
        cout_l[m*HDIM + j] = c;
        const short hb = f2bf(hv);
        hg[(size_t)m*HDIM + j] = hb;
        const int ar = m >> 1;
        const int s  = (m & 1)*HDIM + j;
        hR[ar*256 + (s ^ ((ar & 7) << 3))] = hb;   // becomes next level's A
      }
    }
  }
  __syncthreads();   // h/c visible for next level
}

__global__ __launch_bounds__(512) void tail_kernel(
    short* __restrict__ h_all,
    const float* __restrict__ c128g,   // c of the N=128 level
    const short* __restrict__ Wc, const float* __restrict__ bias)
{
  __shared__ short hR[64*256];    // 32KB: 64 A-rows (=128 h rows)
  __shared__ float cb0[64*HDIM];  // 32KB
  __shared__ float cb1[32*HDIM];  // 16KB
  const int tid = threadIdx.x;

  // stage h of N=128 level (rows 0..127) into hR, swizzled
  const short* h128 = h_all + (size_t)130816*HDIM;
  #pragma unroll
  for (int i = 0; i < 4; ++i){
    const int chunk = i*512 + tid;            // 0..2047 (8-short chunks)
    const int r  = chunk >> 4;
    const int s0 = (chunk & 15)*8;
    const int ar = r >> 1;
    const int s  = (r & 1)*HDIM + s0;
    const s8v v = *reinterpret_cast<const s8v*>(h128 + (size_t)r*HDIM + s0);
    *reinterpret_cast<s8v*>(hR + ar*256 + (s ^ ((ar & 7) << 3))) = v;
  }
  __syncthreads();

  tail_level<64, true >(tid, c128g, nullptr, cb0, hR, h_all + (size_t)130944*HDIM, Wc, bias);
  tail_level<32, false>(tid, nullptr, cb0, cb1, hR, h_all + (size_t)131008*HDIM, Wc, bias);
  tail_level<16, false>(tid, nullptr, cb1, cb0, hR, h_all + (size_t)131040*HDIM, Wc, bias);
  tail_level<8,  false>(tid, nullptr, cb0, cb1, hR, h_all + (size_t)131056*HDIM, Wc, bias);
  tail_level<4,  false>(tid, nullptr, cb1, cb0, hR, h_all + (size_t)131064*HDIM, Wc, bias);
  tail_level<2,  false>(tid, nullptr, cb0, cb1, hR, h_all + (size_t)131068*HDIM, Wc, bias);
  tail_level<1,  false>(tid, nullptr, cb1, cb0, hR, h_all + (size_t)131070*HDIM, Wc, bias);
}

// ---------------------------------------------------------------------------
// Output projection for all nodes + label copy.
// ---------------------------------------------------------------------------
__global__ __launch_bounds__(256) void outproj_kernel(
    const short* __restrict__ h_all,
    const int* __restrict__ labels,
    const float* __restrict__ ow, const float* __restrict__ ob,
    float* __restrict__ out)
{
  __shared__ float wsm[5*HDIM];
  __shared__ float bsm[5];
  for (int i = threadIdx.x; i < 5*HDIM; i += 256) wsm[i] = ow[i];
  if (threadIdx.x < 5) bsm[threadIdx.x] = ob[threadIdx.x];
  __syncthreads();
  const int n = blockIdx.x*256 + threadIdx.x;
  if (n >= TOTAL_NODES) return;
  const s8v* hp = reinterpret_cast<const s8v*>(h_all + (size_t)n*HDIM);
  float acc[5] = {0.f,0.f,0.f,0.f,0.f};
  #pragma unroll
  for (int t = 0; t < 16; ++t){
    const s8v v = hp[t];
    #pragma unroll
    for (int e = 0; e < 8; ++e){
      const float hv = bf2f(v[e]);
      const int j = t*8 + e;
      #pragma unroll
      for (int c5 = 0; c5 < 5; ++c5) acc[c5] += hv * wsm[c5*HDIM + j];
    }
  }
  #pragma unroll
  for (int c5 = 0; c5 < 5; ++c5) out[(size_t)n*5 + c5] = acc[c5] + bsm[c5];
  out[(size_t)TOTAL_NODES*5 + n] = (float)labels[n];
}

// ---------------------------------------------------------------------------
extern "C" void kernel_launch(void* const* d_in, const int* in_sizes, int n_in,
                              void* d_out, int out_size, void* d_ws, size_t ws_size,
                              hipStream_t stream)
{
  (void)in_sizes; (void)n_in; (void)out_size; (void)ws_size;
  const int*   tok    = (const int*)  d_in[0];
  const int*   labels = (const int*)  d_in[1];
  const float* embed  = (const float*)d_in[2];
  const float* Wi  = (const float*)d_in[3];  const float* bi  = (const float*)d_in[4];
  const float* Wo  = (const float*)d_in[5];  const float* bo  = (const float*)d_in[6];
  const float* Wu  = (const float*)d_in[7];  const float* bu  = (const float*)d_in[8];
  const float* Ui  = (const float*)d_in[9];  const float* bUi = (const float*)d_in[10];
  const float* Uo  = (const float*)d_in[11]; const float* bUo = (const float*)d_in[12];
  const float* Uu  = (const float*)d_in[13]; const float* bUu = (const float*)d_in[14];
  const float* F1  = (const float*)d_in[15]; const float* bF1 = (const float*)d_in[16];
  const float* F2  = (const float*)d_in[17]; const float* bF2 = (const float*)d_in[18];
  const float* ow  = (const float*)d_in[19]; const float* ob  = (const float*)d_in[20];
  float* out = (float*)d_out;

  char* ws = (char*)d_ws;
  size_t off = 0;
  auto alloc = [&](size_t bytes) -> void* {
    void* p = ws + off;
    off += (bytes + 255) & ~(size_t)255;
    return p;
  };
  short* h_all  = (short*)alloc((size_t)131072*HDIM*2);
  float* c_a    = (float*)alloc((size_t)65536*HDIM*4);
  float* c_b    = (float*)alloc((size_t)32768*HDIM*4);
  short* Wc_lin = (short*)alloc((size_t)640*256*2);
  short* Wc_st  = (short*)alloc((size_t)640*256*2);
  short* Wl_st  = (short*)alloc((size_t)384*128*2);
  float* bl     = (float*)alloc((size_t)384*4);
  float* bc     = (float*)alloc((size_t)640*4);

  prep_weights<<<640, 256, 0, stream>>>(Wi,bi,Wo,bo,Wu,bu,Ui,bUi,Uo,bUo,Uu,bUu,
                                        F1,bF1,F2,bF2, Wc_lin, Wc_st, Wl_st, bl, bc);

  // Leaf (embed gather fused): K=128, G=3
  level_kernel<128,3,true><<<NLEAVES/128, 256, 0, stream>>>(
      nullptr, tok, embed, nullptr, Wl_st, bl, h_all, c_a);

  // Interior levels N = 32768 .. 128 (L = 1..9)
  size_t prev_off = 0;
  size_t cur_off  = NLEAVES;
  int N = NLEAVES;
  for (int L = 1; L <= 9; ++L){
    N >>= 1;
    const short* Aptr = h_all + prev_off*HDIM;
    short*       hout = h_all + cur_off*HDIM;
    float* cin  = (L & 1) ? c_a : c_b;
    float* cout = (L & 1) ? c_b : c_a;
    level_kernel<256,5,false><<<N/128, 256, 0, stream>>>(
        Aptr, nullptr, nullptr, cin, Wc_st, bc, hout, cout);
    prev_off = cur_off;
    cur_off += N;
  }

  // Tail levels N=64..1 fused in one block. c of N=128 level is in c_b (L=9 odd).
  tail_kernel<<<1, 512, 0, stream>>>(h_all, c_b, Wc_lin, bc);

  outproj_kernel<<<(TOTAL_NODES + 255)/256, 256, 0, stream>>>(h_all, labels, ow, ob, out);
}

// Round 4
// 332.330 us; speedup vs baseline: 3.2308x; 2.0003x over previous
//
#include <hip/hip_runtime.h>
#include <hip/hip_bf16.h>
#include <cstdint>
#include <cstddef>

#define HDIM 128
#define NLEAVES 65536
#define TOTAL_NODES 131071   // 2*NLEAVES - 1

using s8v  = __attribute__((ext_vector_type(8))) short;
using f4v  = __attribute__((ext_vector_type(4))) float;

__device__ __forceinline__ short f2bf(float f){
  __hip_bfloat16 b = __float2bfloat16(f);
  return *reinterpret_cast<short*>(&b);
}
__device__ __forceinline__ float bf2f(short s){
  unsigned int u = ((unsigned int)(unsigned short)s) << 16;
  return __uint_as_float(u);
}
__device__ __forceinline__ float sigm(float x){ return 1.0f/(1.0f + __expf(-x)); }
__device__ __forceinline__ float tanh_(float x){
  float a = fabsf(x);
  float t = __expf(-2.0f*a);
  float r = (1.0f - t)/(1.0f + t);
  return copysignf(r, x);
}
__device__ __forceinline__ void gload_lds16(const void* g, void* l){
  __builtin_amdgcn_global_load_lds(
      (const __attribute__((address_space(1))) unsigned int*)g,
      (__attribute__((address_space(3))) unsigned int*)l, 16, 0, 0);
}

// ---------------------------------------------------------------------------
// Weight prep.
// Wc_lin  [640][256]   : U_i,U_o,U_u,[F1|0],[0|F2]  (plain, for tail kernel)
// Wc_st   [8][80][256] : per-ct slice, rows g*16+r16, shorts k ^ ((r16&7)<<3)
// Wl_st   [8][48][128] : leaf slices, same swizzle
// bl[384], bc[640]
// ---------------------------------------------------------------------------
__global__ __launch_bounds__(256) void prep_weights(
    const float* __restrict__ Wi, const float* __restrict__ bi,
    const float* __restrict__ Wo, const float* __restrict__ bo,
    const float* __restrict__ Wu, const float* __restrict__ bu,
    const float* __restrict__ Ui, const float* __restrict__ bUi,
    const float* __restrict__ Uo, const float* __restrict__ bUo,
    const float* __restrict__ Uu, const float* __restrict__ bUu,
    const float* __restrict__ F1, const float* __restrict__ bF1,
    const float* __restrict__ F2, const float* __restrict__ bF2,
    short* __restrict__ Wc_lin, short* __restrict__ Wc_st,
    short* __restrict__ Wl_st,
    float* __restrict__ bl, float* __restrict__ bc)
{
  const int gid = blockIdx.x*256 + threadIdx.x;   // 640*256 = 163840 threads
  if (gid < 640*256){
    const int row = gid >> 8, k = gid & 255;
    const int g = row >> 7, jj = row & 127;
    const int ct = jj >> 4, r16 = jj & 15;
    float v;
    if      (g == 0) v = Ui[jj*256 + k];
    else if (g == 1) v = Uo[jj*256 + k];
    else if (g == 2) v = Uu[jj*256 + k];
    else if (g == 3) v = (k < 128) ? F1[jj*128 + k] : 0.0f;
    else             v = (k >= 128) ? F2[jj*128 + (k-128)] : 0.0f;
    const short s = f2bf(v);
    Wc_lin[gid] = s;
    Wc_st[ct*20480 + (g*16 + r16)*256 + (k ^ ((r16 & 7) << 3))] = s;
  }
  if (gid < 384*128){
    const int row = gid >> 7, k = gid & 127;
    const int g = row >> 7, jj = row & 127;
    const int ct = jj >> 4, r16 = jj & 15;
    const float v = (g == 0) ? Wi[jj*128 + k] : (g == 1) ? Wo[jj*128 + k] : Wu[jj*128 + k];
    Wl_st[ct*6144 + (g*16 + r16)*128 + (k ^ ((r16 & 7) << 3))] = f2bf(v);
  }
  if (gid < 640){
    const int g = gid >> 7, j = gid & 127;
    bc[gid] = (g==0)?bUi[j]:(g==1)?bUo[j]:(g==2)?bUu[j]:(g==3)?bF1[j]:bF2[j];
  }
  if (gid < 384){
    const int g = gid >> 7, j = gid & 127;
    bl[gid] = (g==0)?bi[j]:(g==1)?bo[j]:bu[j];
  }
}

// ---------------------------------------------------------------------------
// Leaf kernel: embed-gather fused, ct-loop with double-buffered 12KB B slices.
// 256 thr = 4 waves; wave = 32 nodes; block = 128 nodes.
// c_out layout: [8 ct][NLEAVES][16] f32.
// ---------------------------------------------------------------------------
__global__ __launch_bounds__(256) void leaf_kernel(
    const int*   __restrict__ tok,
    const float* __restrict__ embed,
    const short* __restrict__ Wst,    // [8][48][128] swizzled
    const float* __restrict__ bias,   // [384]
    short* __restrict__ h_out,
    float* __restrict__ c_out)
{
  constexpr int K = 128, G = 3;
  constexpr int SLICE = G*16*K;          // 6144 shorts
  __shared__ short Bst[2][SLICE];

  const int tid  = threadIdx.x;
  const int lane = tid & 63;
  const int wv   = tid >> 6;
  const int r16  = lane & 15;
  const int kg   = lane >> 4;
  const int m0   = blockIdx.x*128 + wv*32;
  const int swz  = (r16 & 7) << 3;

  auto stage = [&](int buf, int ct){
    const short* src = Wst + ct*SLICE;
    #pragma unroll
    for (int i = 0; i < 3; ++i){
      const short* g = src + (size_t)(i*256 + tid)*8;
      short* l = &Bst[buf][0] + (i*256 + wv*64)*8;
      gload_lds16(g, l);
    }
  };

  // A fragments from embed gather
  s8v a[2][4];
  #pragma unroll
  for (int ms = 0; ms < 2; ++ms){
    const int m = m0 + ms*16 + r16;
    const int t = tok[m];
    const float* ep = embed + (size_t)t*HDIM + kg*8;
    #pragma unroll
    for (int kt = 0; kt < 4; ++kt){
      const float4 v0 = *reinterpret_cast<const float4*>(ep + kt*32);
      const float4 v1 = *reinterpret_cast<const float4*>(ep + kt*32 + 4);
      s8v v;
      v[0]=f2bf(v0.x); v[1]=f2bf(v0.y); v[2]=f2bf(v0.z); v[3]=f2bf(v0.w);
      v[4]=f2bf(v1.x); v[5]=f2bf(v1.y); v[6]=f2bf(v1.z); v[7]=f2bf(v1.w);
      a[ms][kt] = v;
    }
  }

  stage(0, 0);
  __syncthreads();

  for (int ct = 0; ct < 8; ++ct){
    const int buf = ct & 1;
    if (ct < 7) stage(buf ^ 1, ct + 1);

    f4v acc[G][2];
    #pragma unroll
    for (int g = 0; g < G; ++g)
      #pragma unroll
      for (int ms = 0; ms < 2; ++ms)
        #pragma unroll
        for (int e = 0; e < 4; ++e) acc[g][ms][e] = 0.0f;

    #pragma unroll
    for (int g = 0; g < G; ++g){
      const short* bp = &Bst[buf][(g*16 + r16)*K];
      #pragma unroll
      for (int kt = 0; kt < 4; ++kt){
        const s8v b = *reinterpret_cast<const s8v*>(bp + ((kg*8 + kt*32) ^ swz));
        acc[g][0] = __builtin_amdgcn_mfma_f32_16x16x32_bf16(a[0][kt], b, acc[g][0], 0, 0, 0);
        acc[g][1] = __builtin_amdgcn_mfma_f32_16x16x32_bf16(a[1][kt], b, acc[g][1], 0, 0, 0);
      }
    }

    const int j = ct*16 + r16;
    const float bi_ = bias[j];
    const float bo_ = bias[HDIM + j];
    const float bu_ = bias[2*HDIM + j];

    #pragma unroll
    for (int ms = 0; ms < 2; ++ms){
      #pragma unroll
      for (int r = 0; r < 4; ++r){
        const int m = m0 + ms*16 + kg*4 + r;
        const float iv = sigm(acc[0][ms][r] + bi_);
        const float ov = sigm(acc[1][ms][r] + bo_);
        const float uv = tanh_(acc[2][ms][r] + bu_);
        const float c  = iv*uv;
        const float hv = ov * tanh_(c);
        c_out[((size_t)ct*NLEAVES + m)*16 + r16] = c;
        h_out[(size_t)m*HDIM + j] = f2bf(hv);
      }
    }
    __syncthreads();
  }
}

// ---------------------------------------------------------------------------
// Interior level kernel: grid = (M/128) * 8 ct-blocks; bid%8 = ct (XCD-affine).
// B slice (40KB) staged ONCE into LDS; A fragments from global (prev h).
// c layouts: c_in [8][2M][16], c_out [8][M][16].
// ---------------------------------------------------------------------------
__global__ __launch_bounds__(256) void level_ct_kernel(
    const short* __restrict__ A,      // [M][256] bf16 (prev-level h pairs)
    const float* __restrict__ c_in,   // [8][2M][16]
    const short* __restrict__ Wst,    // [8][80][256] swizzled
    const float* __restrict__ bias,   // [640]
    short* __restrict__ h_out,        // [M][128]
    float* __restrict__ c_out,        // [8][M][16]
    int M)
{
  __shared__ short Bs[80*256];        // 40KB

  const int tid  = threadIdx.x;
  const int bid  = blockIdx.x;
  const int ct   = bid & 7;
  const int mi   = bid >> 3;
  const int lane = tid & 63;
  const int wv   = tid >> 6;
  const int r16  = lane & 15;
  const int kg   = lane >> 4;
  const int m0   = mi*128 + wv*32;
  const int swz  = (r16 & 7) << 3;

  // stage B slice once
  {
    const short* src = Wst + ct*20480;
    #pragma unroll
    for (int i = 0; i < 10; ++i){
      const short* g = src + (size_t)(i*256 + tid)*8;
      short* l = Bs + (i*256 + wv*64)*8;
      gload_lds16(g, l);
    }
  }

  // A fragments (overlap with staging)
  s8v a[2][8];
  #pragma unroll
  for (int ms = 0; ms < 2; ++ms){
    const short* ap = A + (size_t)(m0 + ms*16 + r16)*256 + kg*8;
    #pragma unroll
    for (int kt = 0; kt < 8; ++kt)
      a[ms][kt] = *reinterpret_cast<const s8v*>(ap + kt*32);
  }
  __syncthreads();

  f4v acc[5][2];
  #pragma unroll
  for (int g = 0; g < 5; ++g)
    #pragma unroll
    for (int ms = 0; ms < 2; ++ms)
      #pragma unroll
      for (int e = 0; e < 4; ++e) acc[g][ms][e] = 0.0f;

  #pragma unroll
  for (int g = 0; g < 5; ++g){
    const short* bp = Bs + (g*16 + r16)*256;
    #pragma unroll
    for (int kt = 0; kt < 8; ++kt){
      const s8v b = *reinterpret_cast<const s8v*>(bp + ((kg*8 + kt*32) ^ swz));
      acc[g][0] = __builtin_amdgcn_mfma_f32_16x16x32_bf16(a[0][kt], b, acc[g][0], 0, 0, 0);
      acc[g][1] = __builtin_amdgcn_mfma_f32_16x16x32_bf16(a[1][kt], b, acc[g][1], 0, 0, 0);
    }
  }

  const int j = ct*16 + r16;
  const float bi_  = bias[j];
  const float bo_  = bias[HDIM + j];
  const float bu_  = bias[2*HDIM + j];
  const float bf1_ = bias[3*HDIM + j];
  const float bf2_ = bias[4*HDIM + j];

  #pragma unroll
  for (int ms = 0; ms < 2; ++ms){
    #pragma unroll
    for (int r = 0; r < 4; ++r){
      const int m = m0 + ms*16 + kg*4 + r;
      const float iv = sigm(acc[0][ms][r] + bi_);
      const float ov = sigm(acc[1][ms][r] + bo_);
      const float uv = tanh_(acc[2][ms][r] + bu_);
      const float f1 = sigm(acc[3][ms][r] + bf1_);
      const float f2 = sigm(acc[4][ms][r] + bf2_);
      const float cl = c_in[((size_t)ct*(2*M) + 2*m    )*16 + r16];
      const float cr = c_in[((size_t)ct*(2*M) + 2*m + 1)*16 + r16];
      const float c  = iv*uv + f1*cl + f2*cr;
      const float hv = ov * tanh_(c);
      c_out[((size_t)ct*M + m)*16 + r16] = c;
      h_out[(size_t)m*HDIM + j] = f2bf(hv);
    }
  }
}

// ---------------------------------------------------------------------------
// Fused tail: levels N=64..1, ONE block, 512 thr = 8 waves (wave = ct slice).
// Weights register-resident for the whole kernel (32 s8v/lane, F compact).
// A-frags loaded once per m-tile, reused across all 5 gates.
// Level 64 runs as 2 register passes (rows 0-31, 32-63) to cap VGPRs.
// ---------------------------------------------------------------------------
template<int N>
__device__ __forceinline__ void tail_level(
    const int ct, const int r16, const int kg, const int j,
    const float* __restrict__ cin, const int cinR,
    float* __restrict__ cout, const int coutR,
    short* __restrict__ hR,
    short* __restrict__ hg,
    const s8v biou[3][8], const s8v bf[2][4],
    const float bi_, const float bo_, const float bu_,
    const float bf1_, const float bf2_)
{
  constexpr int NT     = (N >= 32) ? 2 : 1;
  constexpr int PASSES = (N == 64) ? 2 : 1;

  #pragma unroll
  for (int p = 0; p < PASSES; ++p){
    f4v acc[5][NT];
    #pragma unroll
    for (int g = 0; g < 5; ++g)
      #pragma unroll
      for (int mt = 0; mt < NT; ++mt)
        #pragma unroll
        for (int e = 0; e < 4; ++e) acc[g][mt][e] = 0.0f;

    #pragma unroll
    for (int mt = 0; mt < NT; ++mt){
      const int ar = p*32 + mt*16 + r16;
      const short* hp = hR + ar*256;
      const int sw = (ar & 7) << 3;
      s8v av[8];
      #pragma unroll
      for (int kt = 0; kt < 8; ++kt)
        av[kt] = *reinterpret_cast<const s8v*>(hp + ((kg*8 + kt*32) ^ sw));
      #pragma unroll
      for (int kt = 0; kt < 8; ++kt){
        acc[0][mt] = __builtin_amdgcn_mfma_f32_16x16x32_bf16(av[kt], biou[0][kt], acc[0][mt], 0,0,0);
        acc[1][mt] = __builtin_amdgcn_mfma_f32_16x16x32_bf16(av[kt], biou[1][kt], acc[1][mt], 0,0,0);
        acc[2][mt] = __builtin_amdgcn_mfma_f32_16x16x32_bf16(av[kt], biou[2][kt], acc[2][mt], 0,0,0);
      }
      #pragma unroll
      for (int kt = 0; kt < 4; ++kt){
        acc[3][mt] = __builtin_amdgcn_mfma_f32_16x16x32_bf16(av[kt],   bf[0][kt], acc[3][mt], 0,0,0);
        acc[4][mt] = __builtin_amdgcn_mfma_f32_16x16x32_bf16(av[kt+4], bf[1][kt], acc[4][mt], 0,0,0);
      }
    }

    __syncthreads();   // all hR reads done before overwrites

    #pragma unroll
    for (int mt = 0; mt < NT; ++mt){
      #pragma unroll
      for (int r = 0; r < 4; ++r){
        const int m = p*32 + mt*16 + kg*4 + r;
        if (m < N){
          const float iv = sigm(acc[0][mt][r] + bi_);
          const float ov = sigm(acc[1][mt][r] + bo_);
          const float uv = tanh_(acc[2][mt][r] + bu_);
          const float f1 = sigm(acc[3][mt][r] + bf1_);
          const float f2 = sigm(acc[4][mt][r] + bf2_);
          const float cl = cin[(ct*cinR + 2*m    )*16 + r16];
          const float cr = cin[(ct*cinR + 2*m + 1)*16 + r16];
          const float c  = iv*uv + f1*cl + f2*cr;
          const float hv = ov * tanh_(c);
          cout[(ct*coutR + m)*16 + r16] = c;
          const short hb = f2bf(hv);
          hg[(size_t)m*HDIM + j] = hb;
          const int ar2 = m >> 1;
          const int s   = (m & 1)*HDIM + j;
          hR[ar2*256 + (s ^ ((ar2 & 7) << 3))] = hb;
        }
      }
    }
    __syncthreads();
  }
}

__global__ __launch_bounds__(512, 1) void tail_kernel(
    short* __restrict__ h_all,
    const float* __restrict__ c128g,   // [8][128][16] = c of the N=128 level
    const short* __restrict__ Wc,      // [640][256] linear
    const float* __restrict__ bias)
{
  __shared__ short hR[64*256];      // 32KB
  __shared__ float cb0[8*64*16];    // 32KB
  __shared__ float cb1[8*32*16];    // 16KB
  const int tid  = threadIdx.x;
  const int lane = tid & 63;
  const int ct   = tid >> 6;        // 8 waves = 8 ct slices
  const int r16  = lane & 15;
  const int kg   = lane >> 4;
  const int j    = ct*16 + r16;

  // register-resident weights (loaded once)
  s8v biou[3][8];
  s8v bf[2][4];
  #pragma unroll
  for (int g = 0; g < 3; ++g){
    const short* bp = Wc + (size_t)(g*128 + j)*256 + kg*8;
    #pragma unroll
    for (int kt = 0; kt < 8; ++kt)
      biou[g][kt] = *reinterpret_cast<const s8v*>(bp + kt*32);
  }
  {
    const short* bp1 = Wc + (size_t)(3*128 + j)*256 + kg*8;          // F1: cols 0..127
    const short* bp2 = Wc + (size_t)(4*128 + j)*256 + 128 + kg*8;    // F2: cols 128..255
    #pragma unroll
    for (int kt = 0; kt < 4; ++kt){
      bf[0][kt] = *reinterpret_cast<const s8v*>(bp1 + kt*32);
      bf[1][kt] = *reinterpret_cast<const s8v*>(bp2 + kt*32);
    }
  }
  const float bi_  = bias[j];
  const float bo_  = bias[HDIM + j];
  const float bu_  = bias[2*HDIM + j];
  const float bf1_ = bias[3*HDIM + j];
  const float bf2_ = bias[4*HDIM + j];

  // stage h of the N=128 level into hR (pair-packed, swizzled)
  const short* h128 = h_all + (size_t)130816*HDIM;
  #pragma unroll
  for (int i = 0; i < 4; ++i){
    const int chunk = i*512 + tid;            // 2048 chunks of 8 shorts
    const int r  = chunk >> 4;
    const int s0 = (chunk & 15)*8;
    const int ar = r >> 1;
    const int s  = (r & 1)*HDIM + s0;
    const s8v v = *reinterpret_cast<const s8v*>(h128 + (size_t)r*HDIM + s0);
    *reinterpret_cast<s8v*>(hR + ar*256 + (s ^ ((ar & 7) << 3))) = v;
  }
  __syncthreads();

  tail_level<64>(ct, r16, kg, j, c128g, 128, cb0, 64, hR, h_all + (size_t)130944*HDIM, biou, bf, bi_,bo_,bu_,bf1_,bf2_);
  tail_level<32>(ct, r16, kg, j, cb0,    64, cb1, 32, hR, h_all + (size_t)131008*HDIM, biou, bf, bi_,bo_,bu_,bf1_,bf2_);
  tail_level<16>(ct, r16, kg, j, cb1,    32, cb0, 16, hR, h_all + (size_t)131040*HDIM, biou, bf, bi_,bo_,bu_,bf1_,bf2_);
  tail_level<8 >(ct, r16, kg, j, cb0,    16, cb1,  8, hR, h_all + (size_t)131056*HDIM, biou, bf, bi_,bo_,bu_,bf1_,bf2_);
  tail_level<4 >(ct, r16, kg, j, cb1,     8, cb0,  4, hR, h_all + (size_t)131064*HDIM, biou, bf, bi_,bo_,bu_,bf1_,bf2_);
  tail_level<2 >(ct, r16, kg, j, cb0,     4, cb1,  2, hR, h_all + (size_t)131068*HDIM, biou, bf, bi_,bo_,bu_,bf1_,bf2_);
  tail_level<1 >(ct, r16, kg, j, cb1,     2, cb0,  1, hR, h_all + (size_t)131070*HDIM, biou, bf, bi_,bo_,bu_,bf1_,bf2_);
}

// ---------------------------------------------------------------------------
// Output projection for all nodes + label copy.
// ---------------------------------------------------------------------------
__global__ __launch_bounds__(256) void outproj_kernel(
    const short* __restrict__ h_all,
    const int* __restrict__ labels,
    const float* __restrict__ ow, const float* __restrict__ ob,
    float* __restrict__ out)
{
  __shared__ float wsm[5*HDIM];
  __shared__ float bsm[5];
  for (int i = threadIdx.x; i < 5*HDIM; i += 256) wsm[i] = ow[i];
  if (threadIdx.x < 5) bsm[threadIdx.x] = ob[threadIdx.x];
  __syncthreads();
  const int n = blockIdx.x*256 + threadIdx.x;
  if (n >= TOTAL_NODES) return;
  const s8v* hp = reinterpret_cast<const s8v*>(h_all + (size_t)n*HDIM);
  float acc[5] = {0.f,0.f,0.f,0.f,0.f};
  #pragma unroll
  for (int t = 0; t < 16; ++t){
    const s8v v = hp[t];
    #pragma unroll
    for (int e = 0; e < 8; ++e){
      const float hv = bf2f(v[e]);
      const int jj = t*8 + e;
      #pragma unroll
      for (int c5 = 0; c5 < 5; ++c5) acc[c5] += hv * wsm[c5*HDIM + jj];
    }
  }
  #pragma unroll
  for (int c5 = 0; c5 < 5; ++c5) out[(size_t)n*5 + c5] = acc[c5] + bsm[c5];
  out[(size_t)TOTAL_NODES*5 + n] = (float)labels[n];
}

// ---------------------------------------------------------------------------
extern "C" void kernel_launch(void* const* d_in, const int* in_sizes, int n_in,
                              void* d_out, int out_size, void* d_ws, size_t ws_size,
                              hipStream_t stream)
{
  (void)in_sizes; (void)n_in; (void)out_size; (void)ws_size;
  const int*   tok    = (const int*)  d_in[0];
  const int*   labels = (const int*)  d_in[1];
  const float* embed  = (const float*)d_in[2];
  const float* Wi  = (const float*)d_in[3];  const float* bi  = (const float*)d_in[4];
  const float* Wo  = (const float*)d_in[5];  const float* bo  = (const float*)d_in[6];
  const float* Wu  = (const float*)d_in[7];  const float* bu  = (const float*)d_in[8];
  const float* Ui  = (const float*)d_in[9];  const float* bUi = (const float*)d_in[10];
  const float* Uo  = (const float*)d_in[11]; const float* bUo = (const float*)d_in[12];
  const float* Uu  = (const float*)d_in[13]; const float* bUu = (const float*)d_in[14];
  const float* F1  = (const float*)d_in[15]; const float* bF1 = (const float*)d_in[16];
  const float* F2  = (const float*)d_in[17]; const float* bF2 = (const float*)d_in[18];
  const float* ow  = (const float*)d_in[19]; const float* ob  = (const float*)d_in[20];
  float* out = (float*)d_out;

  char* ws = (char*)d_ws;
  size_t off = 0;
  auto alloc = [&](size_t bytes) -> void* {
    void* p = ws + off;
    off += (bytes + 255) & ~(size_t)255;
    return p;
  };
  short* h_all  = (short*)alloc((size_t)131072*HDIM*2);
  float* c_a    = (float*)alloc((size_t)65536*HDIM*4);
  float* c_b    = (float*)alloc((size_t)32768*HDIM*4);
  short* Wc_lin = (short*)alloc((size_t)640*256*2);
  short* Wc_st  = (short*)alloc((size_t)640*256*2);
  short* Wl_st  = (short*)alloc((size_t)384*128*2);
  float* bl     = (float*)alloc((size_t)384*4);
  float* bc     = (float*)alloc((size_t)640*4);

  prep_weights<<<640, 256, 0, stream>>>(Wi,bi,Wo,bo,Wu,bu,Ui,bUi,Uo,bUo,Uu,bUu,
                                        F1,bF1,F2,bF2, Wc_lin, Wc_st, Wl_st, bl, bc);

  leaf_kernel<<<NLEAVES/128, 256, 0, stream>>>(tok, embed, Wl_st, bl, h_all, c_a);

  // Interior levels N = 32768 .. 128 (L = 1..9), grid = (N/128)*8 ct-blocks
  size_t prev_off = 0;
  size_t cur_off  = NLEAVES;
  int N = NLEAVES;
  for (int L = 1; L <= 9; ++L){
    N >>= 1;
    const short* Aptr = h_all + prev_off*HDIM;
    short*       hout = h_all + cur_off*HDIM;
    float* cin  = (L & 1) ? c_a : c_b;
    float* cout = (L & 1) ? c_b : c_a;
    level_ct_kernel<<<(N/128)*8, 256, 0, stream>>>(
        Aptr, cin, Wc_st, bc, hout, cout, N);
    prev_off = cur_off;
    cur_off += N;
  }

  // Tail levels N=64..1 (c of N=128 level is in c_b, layout [8][128][16])
  tail_kernel<<<1, 512, 0, stream>>>(h_all, c_b, Wc_lin, bc);

  outproj_kernel<<<(TOTAL_NODES + 255)/256, 256, 0, stream>>>(h_all, labels, ow, ob, out);
}

// Round 5
// 272.813 us; speedup vs baseline: 3.9356x; 1.2182x over previous
//
#include <hip/hip_runtime.h>
#include <hip/hip_bf16.h>
#include <cstdint>
#include <cstddef>

#define HDIM 128
#define NLEAVES 65536
#define TOTAL_NODES 131071   // 2*NLEAVES - 1

using s8v  = __attribute__((ext_vector_type(8))) short;
using f4v  = __attribute__((ext_vector_type(4))) float;

__device__ __forceinline__ short f2bf(float f){
  __hip_bfloat16 b = __float2bfloat16(f);
  return *reinterpret_cast<short*>(&b);
}
__device__ __forceinline__ float sigm(float x){ return 1.0f/(1.0f + __expf(-x)); }
__device__ __forceinline__ float tanh_(float x){
  float a = fabsf(x);
  float t = __expf(-2.0f*a);
  float r = (1.0f - t)/(1.0f + t);
  return copysignf(r, x);
}
__device__ __forceinline__ float bf2f(short s){
  unsigned int u = ((unsigned int)(unsigned short)s) << 16;
  return __uint_as_float(u);
}

// ---------------------------------------------------------------------------
// Weight prep (plain linear layouts only).
// Wl_lin [384][128] : W_i, W_o, W_u
// Wc_lin [640][256] : U_i, U_o, U_u, [F1|0], [0|F2]
// bl[384], bc[640]
// ---------------------------------------------------------------------------
__global__ __launch_bounds__(256) void prep_weights(
    const float* __restrict__ Wi, const float* __restrict__ bi,
    const float* __restrict__ Wo, const float* __restrict__ bo,
    const float* __restrict__ Wu, const float* __restrict__ bu,
    const float* __restrict__ Ui, const float* __restrict__ bUi,
    const float* __restrict__ Uo, const float* __restrict__ bUo,
    const float* __restrict__ Uu, const float* __restrict__ bUu,
    const float* __restrict__ F1, const float* __restrict__ bF1,
    const float* __restrict__ F2, const float* __restrict__ bF2,
    short* __restrict__ Wl_lin, short* __restrict__ Wc_lin,
    float* __restrict__ bl, float* __restrict__ bc)
{
  const int gid = blockIdx.x*256 + threadIdx.x;   // 640*256 = 163840
  if (gid < 640*256){
    const int row = gid >> 8, k = gid & 255;
    const int g = row >> 7, jj = row & 127;
    float v;
    if      (g == 0) v = Ui[jj*256 + k];
    else if (g == 1) v = Uo[jj*256 + k];
    else if (g == 2) v = Uu[jj*256 + k];
    else if (g == 3) v = (k < 128) ? F1[jj*128 + k] : 0.0f;
    else             v = (k >= 128) ? F2[jj*128 + (k-128)] : 0.0f;
    Wc_lin[gid] = f2bf(v);
  }
  if (gid < 384*128){
    const int row = gid >> 7, k = gid & 127;
    const int g = row >> 7, jj = row & 127;
    const float v = (g == 0) ? Wi[jj*128 + k] : (g == 1) ? Wo[jj*128 + k] : Wu[jj*128 + k];
    Wl_lin[gid] = f2bf(v);
  }
  if (gid < 640){
    const int g = gid >> 7, j = gid & 127;
    bc[gid] = (g==0)?bUi[j]:(g==1)?bUo[j]:(g==2)?bUu[j]:(g==3)?bF1[j]:bF2[j];
  }
  if (gid < 384){
    const int g = gid >> 7, j = gid & 127;
    bl[gid] = (g==0)?bi[j]:(g==1)?bo[j]:bu[j];
  }
}

// ---------------------------------------------------------------------------
// One binary-tree level (N nodes) with A (pair-packed h, swizzled) in AL.
// 8 waves = 8 ct channel slices. Weights register-resident.
// c layout: [node][128] f32 (LDS or global). Writes next level's A into AL.
// ---------------------------------------------------------------------------
template<int N>
__device__ __forceinline__ void seg_level(
    const int ct, const int r16, const int kg, const int j,
    const float* cin,            // [2N][128]
    float*       cout,           // [N][128]
    short* AL,                   // A rows [N][256] swizzled; next written in place
    short* hg,                   // global h section for this level
    const s8v (&biou)[3][8], const s8v (&bf)[2][4],
    const float bi_, const float bo_, const float bu_,
    const float bf1_, const float bf2_)
{
  constexpr int PASSES = (N == 64) ? 2 : 1;
  constexpr int NT     = (N >= 32) ? 2 : 1;

  #pragma unroll
  for (int p = 0; p < PASSES; ++p){
    f4v acc[5][NT];
    #pragma unroll
    for (int g = 0; g < 5; ++g)
      #pragma unroll
      for (int mt = 0; mt < NT; ++mt)
        #pragma unroll
        for (int e = 0; e < 4; ++e) acc[g][mt][e] = 0.0f;

    #pragma unroll
    for (int mt = 0; mt < NT; ++mt){
      const int ar = p*32 + mt*16 + r16;
      const short* hp = AL + ar*256;
      const int sw = (ar & 7) << 3;
      s8v av[8];
      #pragma unroll
      for (int kt = 0; kt < 8; ++kt)
        av[kt] = *reinterpret_cast<const s8v*>(hp + ((kg*8 + kt*32) ^ sw));
      #pragma unroll
      for (int kt = 0; kt < 8; ++kt){
        acc[0][mt] = __builtin_amdgcn_mfma_f32_16x16x32_bf16(av[kt], biou[0][kt], acc[0][mt], 0,0,0);
        acc[1][mt] = __builtin_amdgcn_mfma_f32_16x16x32_bf16(av[kt], biou[1][kt], acc[1][mt], 0,0,0);
        acc[2][mt] = __builtin_amdgcn_mfma_f32_16x16x32_bf16(av[kt], biou[2][kt], acc[2][mt], 0,0,0);
      }
      #pragma unroll
      for (int kt = 0; kt < 4; ++kt){
        acc[3][mt] = __builtin_amdgcn_mfma_f32_16x16x32_bf16(av[kt],   bf[0][kt], acc[3][mt], 0,0,0);
        acc[4][mt] = __builtin_amdgcn_mfma_f32_16x16x32_bf16(av[kt+4], bf[1][kt], acc[4][mt], 0,0,0);
      }
    }

    __syncthreads();   // all AL/cin reads done before overwrites

    #pragma unroll
    for (int mt = 0; mt < NT; ++mt){
      #pragma unroll
      for (int r = 0; r < 4; ++r){
        const int m = p*32 + mt*16 + kg*4 + r;
        if (m < N){
          const float iv = sigm(acc[0][mt][r] + bi_);
          const float ov = sigm(acc[1][mt][r] + bo_);
          const float uv = tanh_(acc[2][mt][r] + bu_);
          const float f1 = sigm(acc[3][mt][r] + bf1_);
          const float f2 = sigm(acc[4][mt][r] + bf2_);
          const float cl = cin[(2*m    )*HDIM + j];
          const float cr = cin[(2*m + 1)*HDIM + j];
          const float c  = iv*uv + f1*cl + f2*cr;
          const float hv = ov * tanh_(c);
          cout[m*HDIM + j] = c;
          const short hb = f2bf(hv);
          hg[(size_t)m*HDIM + j] = hb;
          const int ar2 = m >> 1;
          const int s   = (m & 1)*HDIM + j;
          AL[ar2*256 + (s ^ ((ar2 & 7) << 3))] = hb;
        }
      }
    }
    __syncthreads();
  }
}

// ---------------------------------------------------------------------------
// Kernel A: one block = one 128-leaf subtree; leaf + global levels 1..7.
// ---------------------------------------------------------------------------
__global__ __launch_bounds__(512) void subtree_kernel(
    const int*   __restrict__ tok,
    const float* __restrict__ embed,
    const short* __restrict__ Wl,   // [384][128]
    const short* __restrict__ Wc,   // [640][256]
    const float* __restrict__ bl,
    const float* __restrict__ bc,
    short* __restrict__ h_all,
    float* __restrict__ croot1)     // [512][128]
{
  __shared__ short AL[64*256];      // 32KB (leaf phase: 128 rows x 128)
  __shared__ float cb0[128*HDIM];   // 64KB
  __shared__ float cb1[64*HDIM];    // 32KB

  const int tid  = threadIdx.x;
  const int lane = tid & 63;
  const int ct   = tid >> 6;
  const int r16  = lane & 15;
  const int kg   = lane >> 4;
  const int j    = ct*16 + r16;
  const int bid  = blockIdx.x;

  const float lbi = bl[j], lbo = bl[HDIM + j], lbu = bl[2*HDIM + j];
  const float bi_ = bc[j], bo_ = bc[HDIM + j], bu_ = bc[2*HDIM + j];
  const float bf1_ = bc[3*HDIM + j], bf2_ = bc[4*HDIM + j];

  // leaf weights in registers
  s8v wl[3][4];
  #pragma unroll
  for (int g = 0; g < 3; ++g){
    const short* bp = Wl + (size_t)(g*128 + j)*128 + kg*8;
    #pragma unroll
    for (int kt = 0; kt < 4; ++kt)
      wl[g][kt] = *reinterpret_cast<const s8v*>(bp + kt*32);
  }

  // stage 128 embedding rows into AL (leaf layout: row r, 128 shorts, swizzled)
  #pragma unroll
  for (int ii = 0; ii < 4; ++ii){
    const int chunk = ii*512 + tid;      // 2048 chunks of 8 shorts
    const int r  = chunk >> 4;
    const int s0 = (chunk & 15)*8;
    const int t  = tok[bid*128 + r];
    const float* ep = embed + (size_t)t*HDIM + s0;
    const float4 v0 = *reinterpret_cast<const float4*>(ep);
    const float4 v1 = *reinterpret_cast<const float4*>(ep + 4);
    s8v v;
    v[0]=f2bf(v0.x); v[1]=f2bf(v0.y); v[2]=f2bf(v0.z); v[3]=f2bf(v0.w);
    v[4]=f2bf(v1.x); v[5]=f2bf(v1.y); v[6]=f2bf(v1.z); v[7]=f2bf(v1.w);
    *reinterpret_cast<s8v*>(AL + r*128 + (s0 ^ ((r & 7) << 3))) = v;
  }
  __syncthreads();

  // leaf level: 2 passes x 4 tiles; writes cb0, global h, and next-A into AL
  #pragma unroll
  for (int p = 0; p < 2; ++p){
    f4v acc[3][4];
    #pragma unroll
    for (int g = 0; g < 3; ++g)
      #pragma unroll
      for (int mt = 0; mt < 4; ++mt)
        #pragma unroll
        for (int e = 0; e < 4; ++e) acc[g][mt][e] = 0.0f;

    #pragma unroll
    for (int mt = 0; mt < 4; ++mt){
      const int ar = p*64 + mt*16 + r16;
      const short* hp = AL + ar*128;
      const int sw = (ar & 7) << 3;
      s8v av[4];
      #pragma unroll
      for (int kt = 0; kt < 4; ++kt)
        av[kt] = *reinterpret_cast<const s8v*>(hp + ((kg*8 + kt*32) ^ sw));
      #pragma unroll
      for (int kt = 0; kt < 4; ++kt){
        acc[0][mt] = __builtin_amdgcn_mfma_f32_16x16x32_bf16(av[kt], wl[0][kt], acc[0][mt], 0,0,0);
        acc[1][mt] = __builtin_amdgcn_mfma_f32_16x16x32_bf16(av[kt], wl[1][kt], acc[1][mt], 0,0,0);
        acc[2][mt] = __builtin_amdgcn_mfma_f32_16x16x32_bf16(av[kt], wl[2][kt], acc[2][mt], 0,0,0);
      }
    }
    __syncthreads();
    #pragma unroll
    for (int mt = 0; mt < 4; ++mt){
      #pragma unroll
      for (int r = 0; r < 4; ++r){
        const int m = p*64 + mt*16 + kg*4 + r;
        const float iv = sigm(acc[0][mt][r] + lbi);
        const float ov = sigm(acc[1][mt][r] + lbo);
        const float uv = tanh_(acc[2][mt][r] + lbu);
        const float c  = iv*uv;
        const float hv = ov * tanh_(c);
        cb0[m*HDIM + j] = c;
        const short hb = f2bf(hv);
        h_all[(size_t)(bid*128 + m)*HDIM + j] = hb;
        const int ar2 = m >> 1;
        const int s   = (m & 1)*HDIM + j;
        AL[ar2*256 + (s ^ ((ar2 & 7) << 3))] = hb;
      }
    }
    __syncthreads();
  }

  // interior weights in registers
  s8v biou[3][8];
  s8v bf[2][4];
  #pragma unroll
  for (int g = 0; g < 3; ++g){
    const short* bp = Wc + (size_t)(g*128 + j)*256 + kg*8;
    #pragma unroll
    for (int kt = 0; kt < 8; ++kt)
      biou[g][kt] = *reinterpret_cast<const s8v*>(bp + kt*32);
  }
  {
    const short* bp1 = Wc + (size_t)(3*128 + j)*256 + kg*8;
    const short* bp2 = Wc + (size_t)(4*128 + j)*256 + 128 + kg*8;
    #pragma unroll
    for (int kt = 0; kt < 4; ++kt){
      bf[0][kt] = *reinterpret_cast<const s8v*>(bp1 + kt*32);
      bf[1][kt] = *reinterpret_cast<const s8v*>(bp2 + kt*32);
    }
  }

  seg_level<64>(ct,r16,kg,j, cb0, cb1, AL, h_all + (size_t)(65536  + bid*64)*HDIM, biou, bf, bi_,bo_,bu_,bf1_,bf2_);
  seg_level<32>(ct,r16,kg,j, cb1, cb0, AL, h_all + (size_t)(98304  + bid*32)*HDIM, biou, bf, bi_,bo_,bu_,bf1_,bf2_);
  seg_level<16>(ct,r16,kg,j, cb0, cb1, AL, h_all + (size_t)(114688 + bid*16)*HDIM, biou, bf, bi_,bo_,bu_,bf1_,bf2_);
  seg_level<8 >(ct,r16,kg,j, cb1, cb0, AL, h_all + (size_t)(122880 + bid*8 )*HDIM, biou, bf, bi_,bo_,bu_,bf1_,bf2_);
  seg_level<4 >(ct,r16,kg,j, cb0, cb1, AL, h_all + (size_t)(126976 + bid*4 )*HDIM, biou, bf, bi_,bo_,bu_,bf1_,bf2_);
  seg_level<2 >(ct,r16,kg,j, cb1, cb0, AL, h_all + (size_t)(129024 + bid*2 )*HDIM, biou, bf, bi_,bo_,bu_,bf1_,bf2_);
  seg_level<1 >(ct,r16,kg,j, cb0, croot1 + bid*HDIM, AL, h_all + (size_t)(130048 + bid)*HDIM, biou, bf, bi_,bo_,bu_,bf1_,bf2_);
}

// ---------------------------------------------------------------------------
// Kernel B: 4 blocks x 128 subtree-roots; global levels 8..14.
// ---------------------------------------------------------------------------
__global__ __launch_bounds__(512) void mid_kernel(
    const short* __restrict__ Wc, const float* __restrict__ bc,
    short* __restrict__ h_all,
    const float* __restrict__ croot1,   // [512][128]
    float* __restrict__ croot2)         // [4][128]
{
  __shared__ short AL[64*256];      // 32KB
  __shared__ float cb0[64*HDIM];    // 32KB
  __shared__ float cb1[32*HDIM];    // 16KB

  const int tid  = threadIdx.x;
  const int lane = tid & 63;
  const int ct   = tid >> 6;
  const int r16  = lane & 15;
  const int kg   = lane >> 4;
  const int j    = ct*16 + r16;
  const int b    = blockIdx.x;

  const float bi_ = bc[j], bo_ = bc[HDIM + j], bu_ = bc[2*HDIM + j];
  const float bf1_ = bc[3*HDIM + j], bf2_ = bc[4*HDIM + j];

  s8v biou[3][8];
  s8v bf[2][4];
  #pragma unroll
  for (int g = 0; g < 3; ++g){
    const short* bp = Wc + (size_t)(g*128 + j)*256 + kg*8;
    #pragma unroll
    for (int kt = 0; kt < 8; ++kt)
      biou[g][kt] = *reinterpret_cast<const s8v*>(bp + kt*32);
  }
  {
    const short* bp1 = Wc + (size_t)(3*128 + j)*256 + kg*8;
    const short* bp2 = Wc + (size_t)(4*128 + j)*256 + 128 + kg*8;
    #pragma unroll
    for (int kt = 0; kt < 4; ++kt){
      bf[0][kt] = *reinterpret_cast<const s8v*>(bp1 + kt*32);
      bf[1][kt] = *reinterpret_cast<const s8v*>(bp2 + kt*32);
    }
  }

  // stage 64 A-rows from level-7 h (subtree roots of this block)
  const short* hsrc = h_all + (size_t)(130048 + b*128)*HDIM;
  #pragma unroll
  for (int ii = 0; ii < 4; ++ii){
    const int chunk = ii*512 + tid;       // 2048 chunks (64 rows x 32)
    const int r  = chunk >> 5;
    const int s0 = (chunk & 31)*8;
    const s8v v = *reinterpret_cast<const s8v*>(hsrc + (size_t)(2*r + (s0 >> 7))*HDIM + (s0 & 127));
    *reinterpret_cast<s8v*>(AL + r*256 + (s0 ^ ((r & 7) << 3))) = v;
  }
  __syncthreads();

  seg_level<64>(ct,r16,kg,j, croot1 + (size_t)b*128*HDIM, cb0, AL, h_all + (size_t)(130560 + b*64)*HDIM, biou, bf, bi_,bo_,bu_,bf1_,bf2_);
  seg_level<32>(ct,r16,kg,j, cb0, cb1, AL, h_all + (size_t)(130816 + b*32)*HDIM, biou, bf, bi_,bo_,bu_,bf1_,bf2_);
  seg_level<16>(ct,r16,kg,j, cb1, cb0, AL, h_all + (size_t)(130944 + b*16)*HDIM, biou, bf, bi_,bo_,bu_,bf1_,bf2_);
  seg_level<8 >(ct,r16,kg,j, cb0, cb1, AL, h_all + (size_t)(131008 + b*8 )*HDIM, biou, bf, bi_,bo_,bu_,bf1_,bf2_);
  seg_level<4 >(ct,r16,kg,j, cb1, cb0, AL, h_all + (size_t)(131040 + b*4 )*HDIM, biou, bf, bi_,bo_,bu_,bf1_,bf2_);
  seg_level<2 >(ct,r16,kg,j, cb0, cb1, AL, h_all + (size_t)(131056 + b*2 )*HDIM, biou, bf, bi_,bo_,bu_,bf1_,bf2_);
  seg_level<1 >(ct,r16,kg,j, cb1, croot2 + b*HDIM, AL, h_all + (size_t)(131064 + b)*HDIM, biou, bf, bi_,bo_,bu_,bf1_,bf2_);
}

// ---------------------------------------------------------------------------
// Kernel C: final levels (N=2, N=1) from the 4 mid-roots.
// ---------------------------------------------------------------------------
__global__ __launch_bounds__(512) void top_kernel(
    const short* __restrict__ Wc, const float* __restrict__ bc,
    short* __restrict__ h_all,
    const float* __restrict__ croot2)   // [4][128]
{
  __shared__ short AL[16*256];     // 8KB (tile reads need 16 rows in-bounds)
  __shared__ float cb0[2*HDIM];
  __shared__ float cb1[1*HDIM];

  const int tid  = threadIdx.x;
  const int lane = tid & 63;
  const int ct   = tid >> 6;
  const int r16  = lane & 15;
  const int kg   = lane >> 4;
  const int j    = ct*16 + r16;

  const float bi_ = bc[j], bo_ = bc[HDIM + j], bu_ = bc[2*HDIM + j];
  const float bf1_ = bc[3*HDIM + j], bf2_ = bc[4*HDIM + j];

  s8v biou[3][8];
  s8v bf[2][4];
  #pragma unroll
  for (int g = 0; g < 3; ++g){
    const short* bp = Wc + (size_t)(g*128 + j)*256 + kg*8;
    #pragma unroll
    for (int kt = 0; kt < 8; ++kt)
      biou[g][kt] = *reinterpret_cast<const s8v*>(bp + kt*32);
  }
  {
    const short* bp1 = Wc + (size_t)(3*128 + j)*256 + kg*8;
    const short* bp2 = Wc + (size_t)(4*128 + j)*256 + 128 + kg*8;
    #pragma unroll
    for (int kt = 0; kt < 4; ++kt){
      bf[0][kt] = *reinterpret_cast<const s8v*>(bp1 + kt*32);
      bf[1][kt] = *reinterpret_cast<const s8v*>(bp2 + kt*32);
    }
  }

  // zero AL (garbage rows feed discarded D rows, but keep them finite)
  for (int i = tid; i < 16*256/8; i += 512){
    s8v z; 
    #pragma unroll
    for (int e = 0; e < 8; ++e) z[e] = 0;
    *reinterpret_cast<s8v*>(AL + i*8) = z;
  }
  __syncthreads();
  // stage 2 A-rows from level-14 h (4 nodes)
  if (tid < 64){
    const int r  = tid >> 5;
    const int s0 = (tid & 31)*8;
    const s8v v = *reinterpret_cast<const s8v*>(h_all + (size_t)(131064 + 2*r + (s0 >> 7))*HDIM + (s0 & 127));
    *reinterpret_cast<s8v*>(AL + r*256 + (s0 ^ ((r & 7) << 3))) = v;
  }
  __syncthreads();

  seg_level<2>(ct,r16,kg,j, croot2, cb0, AL, h_all + (size_t)131068*HDIM, biou, bf, bi_,bo_,bu_,bf1_,bf2_);
  seg_level<1>(ct,r16,kg,j, cb0, cb1, AL, h_all + (size_t)131070*HDIM, biou, bf, bi_,bo_,bu_,bf1_,bf2_);
}

// ---------------------------------------------------------------------------
// Output projection for all nodes + label copy.
// ---------------------------------------------------------------------------
__global__ __launch_bounds__(256) void outproj_kernel(
    const short* __restrict__ h_all,
    const int* __restrict__ labels,
    const float* __restrict__ ow, const float* __restrict__ ob,
    float* __restrict__ out)
{
  __shared__ float wsm[5*HDIM];
  __shared__ float bsm[5];
  for (int i = threadIdx.x; i < 5*HDIM; i += 256) wsm[i] = ow[i];
  if (threadIdx.x < 5) bsm[threadIdx.x] = ob[threadIdx.x];
  __syncthreads();
  const int n = blockIdx.x*256 + threadIdx.x;
  if (n >= TOTAL_NODES) return;
  const s8v* hp = reinterpret_cast<const s8v*>(h_all + (size_t)n*HDIM);
  float acc[5] = {0.f,0.f,0.f,0.f,0.f};
  #pragma unroll
  for (int t = 0; t < 16; ++t){
    const s8v v = hp[t];
    #pragma unroll
    for (int e = 0; e < 8; ++e){
      const float hv = bf2f(v[e]);
      const int jj = t*8 + e;
      #pragma unroll
      for (int c5 = 0; c5 < 5; ++c5) acc[c5] += hv * wsm[c5*HDIM + jj];
    }
  }
  #pragma unroll
  for (int c5 = 0; c5 < 5; ++c5) out[(size_t)n*5 + c5] = acc[c5] + bsm[c5];
  out[(size_t)TOTAL_NODES*5 + n] = (float)labels[n];
}

// ---------------------------------------------------------------------------
extern "C" void kernel_launch(void* const* d_in, const int* in_sizes, int n_in,
                              void* d_out, int out_size, void* d_ws, size_t ws_size,
                              hipStream_t stream)
{
  (void)in_sizes; (void)n_in; (void)out_size; (void)ws_size;
  const int*   tok    = (const int*)  d_in[0];
  const int*   labels = (const int*)  d_in[1];
  const float* embed  = (const float*)d_in[2];
  const float* Wi  = (const float*)d_in[3];  const float* bi  = (const float*)d_in[4];
  const float* Wo  = (const float*)d_in[5];  const float* bo  = (const float*)d_in[6];
  const float* Wu  = (const float*)d_in[7];  const float* bu  = (const float*)d_in[8];
  const float* Ui  = (const float*)d_in[9];  const float* bUi = (const float*)d_in[10];
  const float* Uo  = (const float*)d_in[11]; const float* bUo = (const float*)d_in[12];
  const float* Uu  = (const float*)d_in[13]; const float* bUu = (const float*)d_in[14];
  const float* F1  = (const float*)d_in[15]; const float* bF1 = (const float*)d_in[16];
  const float* F2  = (const float*)d_in[17]; const float* bF2 = (const float*)d_in[18];
  const float* ow  = (const float*)d_in[19]; const float* ob  = (const float*)d_in[20];
  float* out = (float*)d_out;

  char* ws = (char*)d_ws;
  size_t off = 0;
  auto alloc = [&](size_t bytes) -> void* {
    void* p = ws + off;
    off += (bytes + 255) & ~(size_t)255;
    return p;
  };
  short* h_all  = (short*)alloc((size_t)131072*HDIM*2);
  float* croot1 = (float*)alloc((size_t)512*HDIM*4);
  float* croot2 = (float*)alloc((size_t)4*HDIM*4);
  short* Wl_lin = (short*)alloc((size_t)384*128*2);
  short* Wc_lin = (short*)alloc((size_t)640*256*2);
  float* bl     = (float*)alloc((size_t)384*4);
  float* bc     = (float*)alloc((size_t)640*4);

  prep_weights<<<640, 256, 0, stream>>>(Wi,bi,Wo,bo,Wu,bu,Ui,bUi,Uo,bUo,Uu,bUu,
                                        F1,bF1,F2,bF2, Wl_lin, Wc_lin, bl, bc);

  subtree_kernel<<<512, 512, 0, stream>>>(tok, embed, Wl_lin, Wc_lin, bl, bc, h_all, croot1);
  mid_kernel<<<4, 512, 0, stream>>>(Wc_lin, bc, h_all, croot1, croot2);
  top_kernel<<<1, 512, 0, stream>>>(Wc_lin, bc, h_all, croot2);

  outproj_kernel<<<(TOTAL_NODES + 255)/256, 256, 0, stream>>>(h_all, labels, ow, ob, out);
}